// Round 9
// baseline (748.996 us; speedup 1.0000x reference)
//
#include <hip/hip_runtime.h>
#include <hip/hip_fp16.h>

#define K_FEATS 128
#define RBSHIFT 9
#define RB 512        // fine-bucket node range (pow2); NB = ceil(n/512) <= 256

typedef short bf16x8 __attribute__((ext_vector_type(8)));
typedef float f32x4 __attribute__((ext_vector_type(4)));

__device__ __forceinline__ unsigned short bf16_rne(float x) {
    unsigned u = __float_as_uint(x);
    unsigned r = (u + 0x7FFFu + ((u >> 16) & 1u)) >> 16;
    return (unsigned short)r;
}
__device__ __forceinline__ float bf16_f(unsigned short h) {
    return __uint_as_float(((unsigned)h) << 16);
}

// ---------------- prep: transpose+split all three W in one dispatch ---------
__global__ __launch_bounds__(256) void split_w3(
    const float* __restrict__ W0, const float* __restrict__ W1,
    const float* __restrict__ W2,
    unsigned short* __restrict__ W0th, unsigned short* __restrict__ W0tl,
    unsigned short* __restrict__ W1th, unsigned short* __restrict__ W1tl,
    unsigned short* __restrict__ W2th, unsigned short* __restrict__ W2tl)
{
    int e = blockIdx.x * 256 + threadIdx.x;
    const float* W;
    unsigned short *Wh, *Wl;
    int NC, idx;
    if (e < 16384)      { W = W0; Wh = W0th; Wl = W0tl; NC = 128; idx = e; }
    else if (e < 32768) { W = W1; Wh = W1th; Wl = W1tl; NC = 128; idx = e - 16384; }
    else if (e < 40960) { W = W2; Wh = W2th; Wl = W2tl; NC = 64;  idx = e - 32768; }
    else return;
    int c = idx >> 7, k = idx & 127;
    float w = W[k * NC + c];
    unsigned short h = bf16_rne(w);
    Wh[idx] = h;
    Wl[idx] = bf16_rne(w - bf16_f(h));
}

// ---------------- coarse count: 256-bin LDS hist per chunk -------------------
__global__ __launch_bounds__(256) void bucket_count(
    const int* __restrict__ src, const int* __restrict__ dst,
    int* __restrict__ partialS, int* __restrict__ partialD,
    int ne, int chunkA, int C, int NB)
{
    __shared__ int h[256];
    int c = blockIdx.x, t = threadIdx.x;
    const int* key = blockIdx.y ? dst : src;
    int* part = blockIdx.y ? partialD : partialS;
    if (t < NB) h[t] = 0;
    __syncthreads();
    int e0 = c * chunkA, e1 = min(ne, e0 + chunkA);
    for (int e = e0 + t; e < e1; e += 256)
        atomicAdd(&h[key[e] >> RBSHIFT], 1);
    __syncthreads();
    for (int i = t; i < NB; i += 256) part[i * C + c] = h[i];
}

__global__ __launch_bounds__(256) void bucket_prefix(
    int* __restrict__ partialS, int* __restrict__ partialD,
    int* __restrict__ totS, int* __restrict__ totD, int C, int NB)
{
    __shared__ int sh[256];
    int b = blockIdx.x, t = threadIdx.x;
    int* part = blockIdx.y ? partialD : partialS;
    int* tot = blockIdx.y ? totD : totS;
    int v = (t < C) ? part[b * C + t] : 0;
    sh[t] = v;
    __syncthreads();
    for (int off = 1; off < 256; off <<= 1) {
        int x = (t >= off) ? sh[t - off] : 0;
        __syncthreads();
        sh[t] += x;
        __syncthreads();
    }
    if (t < C) part[b * C + t] = sh[t] - v;
    if (t == 255) tot[b] = sh[255];
}

__global__ __launch_bounds__(256) void bucket_off_kernel(
    const int* __restrict__ totS, const int* __restrict__ totD,
    int* __restrict__ offS, int* __restrict__ offD,
    int* __restrict__ row_off, int NB, int n, int ne)
{
    __shared__ int sh[256];
    int t = threadIdx.x;
    if (t == 0) row_off[n] = ne;
    for (int a = 0; a < 2; a++) {
        const int* tot = a ? totD : totS;
        int* boff = a ? offD : offS;
        int v = (t < NB) ? tot[t] : 0;
        sh[t] = v;
        __syncthreads();
        for (int off = 1; off < 256; off <<= 1) {
            int x = (t >= off) ? sh[t - off] : 0;
            __syncthreads();
            sh[t] += x;
            __syncthreads();
        }
        if (t < NB) boff[t] = sh[t] - v;
        if (t == NB - 1) boff[NB] = sh[t];
        __syncthreads();
    }
}

// ------- coarse scatter (single pass, both arrays, packed records) ----------
__global__ __launch_bounds__(256) void bucket_scatter(
    const int* __restrict__ src, const int* __restrict__ dst,
    const int* __restrict__ partialS, const int* __restrict__ partialD,
    const int* __restrict__ offS, const int* __restrict__ offD,
    unsigned short* __restrict__ src_bkt, int* __restrict__ edge_bkt,
    int ne, int chunkA, int C, int NB)
{
    __shared__ int curS[256];
    __shared__ int curD[256];
    int c = blockIdx.x, t = threadIdx.x;
    if (t < NB) {
        curS[t] = offS[t] + partialS[t * C + c];
        curD[t] = offD[t] + partialD[t * C + c];
    }
    __syncthreads();
    int e0 = c * chunkA, e1 = min(ne, e0 + chunkA);
    for (int e = e0 + t; e < e1; e += 256) {
        int s = src[e];
        int d = dst[e];
        int posD = atomicAdd(&curD[d >> RBSHIFT], 1);
        edge_bkt[posD] = ((d & (RB - 1)) << 17) | s;
        int posS = atomicAdd(&curS[s >> RBSHIFT], 1);
        src_bkt[posS] = (unsigned short)(s & (RB - 1));
    }
}

// ------- fused fine pass: y=0 dst (hist+scan->row_off/norm_dst + scatter),
//         y=1 src (hist->norm_src) -------------------------------------------
__global__ __launch_bounds__(256) void fine_all(
    const int* __restrict__ edge_bkt, const unsigned short* __restrict__ src_bkt,
    const int* __restrict__ offD, const int* __restrict__ offS,
    int* __restrict__ row_off, float* __restrict__ norm_dst,
    float* __restrict__ norm_src, int* __restrict__ csr, int n)
{
    __shared__ int h[RB];
    __shared__ int ps[256];
    int b = blockIdx.x, t = threadIdx.x;
    int lo = b << RBSHIFT;
    for (int i = t; i < RB; i += 256) h[i] = 0;
    __syncthreads();
    if (blockIdx.y == 1) {
        int e1 = offS[b + 1];
        for (int e = offS[b] + t; e < e1; e += 256)
            atomicAdd(&h[src_bkt[e]], 1);
        __syncthreads();
        for (int i = t; i < RB; i += 256) {
            int g = lo + i;
            if (g < n) norm_src[g] = rsqrtf((float)max(h[i], 1));
        }
        return;
    }
    int ebase = offD[b];
    int e1 = offD[b + 1];
    for (int e = ebase + t; e < e1; e += 256)
        atomicAdd(&h[(unsigned)edge_bkt[e] >> 17], 1);
    __syncthreads();
    int v0 = h[2 * t], v1 = h[2 * t + 1];
    ps[t] = v0 + v1;
    __syncthreads();
    for (int off = 1; off < 256; off <<= 1) {
        int x = (t >= off) ? ps[t - off] : 0;
        __syncthreads();
        ps[t] += x;
        __syncthreads();
    }
    int excl = ps[t] - (v0 + v1) + ebase;
    int g0 = lo + 2 * t, g1 = g0 + 1;
    if (g0 < n) { row_off[g0] = excl;      norm_dst[g0] = rsqrtf((float)max(v0, 1)); }
    if (g1 < n) { row_off[g1] = excl + v0; norm_dst[g1] = rsqrtf((float)max(v1, 1)); }
    h[2 * t] = excl;          // cursors
    h[2 * t + 1] = excl + v0;
    __syncthreads();
    for (int e = ebase + t; e < e1; e += 256) {
        int p = edge_bkt[e];
        int pos = atomicAdd(&h[(unsigned)p >> 17], 1);
        csr[pos] = p & 0x1FFFF;
    }
}

// ---------------- MFMA GEMM: out = scale ⊙ (X @ W), bf16 hi/lo split --------
// F32IN=false: X given as pre-split hi/lo bf16 [n_pad][128].
// F32IN=true:  Xf is fp32 [n][128]; split to hi/lo in-register (guarded).
// W staged in LDS (XOR-swizzled), 3 barriers total.
template <int NCOL, bool HALF_OUT, bool F32IN>
__global__ __launch_bounds__(256) void gemm_mfma(
    const unsigned short* __restrict__ Xh, const unsigned short* __restrict__ Xl,
    const float* __restrict__ Xf,
    const unsigned short* __restrict__ Wth, const unsigned short* __restrict__ Wtl,
    const float* __restrict__ scale, void* __restrict__ outv, int n)
{
    constexpr int CT = NCOL / 16;
    constexpr int CHUNKS = NCOL * 16;          // 16B chunks per half
    __shared__ unsigned short Ws[16 * NCOL * 8];  // [sec][col^(sec&7)][8]

    int t = threadIdx.x;
    int w = t >> 6, lane = t & 63, m = lane & 15, q = lane >> 4;
    int r0 = blockIdx.x * 128 + w * 32;

    f32x4 acc[2][CT];
#pragma unroll
    for (int i = 0; i < 2; i++)
#pragma unroll
        for (int j = 0; j < CT; j++) acc[i][j] = (f32x4){0.f, 0.f, 0.f, 0.f};

    // all A fragments up front
    bf16x8 ah[2][4], al[2][4];
    if (F32IN) {
#pragma unroll
        for (int rt = 0; rt < 2; rt++) {
            int row = r0 + rt * 16 + m;
            bool ok = row < n;
            size_t base = (size_t)row * K_FEATS + q * 8;
#pragma unroll
            for (int k = 0; k < 4; k++) {
                float f[8];
                if (ok) {
                    *(float4*)&f[0] = *(const float4*)(Xf + base + k * 32);
                    *(float4*)&f[4] = *(const float4*)(Xf + base + k * 32 + 4);
                } else {
#pragma unroll
                    for (int j = 0; j < 8; j++) f[j] = 0.f;
                }
                union { bf16x8 v; unsigned short u[8]; } H, L;
#pragma unroll
                for (int j = 0; j < 8; j++) {
                    H.u[j] = bf16_rne(f[j]);
                    L.u[j] = bf16_rne(f[j] - bf16_f(H.u[j]));
                }
                ah[rt][k] = H.v;
                al[rt][k] = L.v;
            }
        }
    } else {
        size_t aoff0 = (size_t)(r0 + m) * K_FEATS + q * 8;
        size_t aoff1 = aoff0 + (size_t)16 * K_FEATS;
#pragma unroll
        for (int k = 0; k < 4; k++) {
            ah[0][k] = *(const bf16x8*)(Xh + aoff0 + k * 32);
            ah[1][k] = *(const bf16x8*)(Xh + aoff1 + k * 32);
            al[0][k] = *(const bf16x8*)(Xl + aoff0 + k * 32);
            al[1][k] = *(const bf16x8*)(Xl + aoff1 + k * 32);
        }
    }

    // stage W-hi
#pragma unroll
    for (int i = 0; i < CHUNKS / 256; i++) {
        int g = t + i * 256;
        int col = g >> 4, sec = g & 15;
        *(bf16x8*)(Ws + sec * NCOL * 8 + ((col ^ (sec & 7)) * 8)) =
            *(const bf16x8*)(Wth + g * 8);
    }
    __syncthreads();
    // phase 1: a_h*b_h + a_l*b_h
#pragma unroll
    for (int k = 0; k < 4; k++) {
        int sec = k * 4 + q;
#pragma unroll
        for (int ct = 0; ct < CT; ct++) {
            bf16x8 bh = *(const bf16x8*)(Ws + sec * NCOL * 8 +
                                         (((ct * 16 + m) ^ (sec & 7)) * 8));
            acc[0][ct] = __builtin_amdgcn_mfma_f32_16x16x32_bf16(ah[0][k], bh, acc[0][ct], 0, 0, 0);
            acc[0][ct] = __builtin_amdgcn_mfma_f32_16x16x32_bf16(al[0][k], bh, acc[0][ct], 0, 0, 0);
            acc[1][ct] = __builtin_amdgcn_mfma_f32_16x16x32_bf16(ah[1][k], bh, acc[1][ct], 0, 0, 0);
            acc[1][ct] = __builtin_amdgcn_mfma_f32_16x16x32_bf16(al[1][k], bh, acc[1][ct], 0, 0, 0);
        }
    }
    __syncthreads();
    // stage W-lo
#pragma unroll
    for (int i = 0; i < CHUNKS / 256; i++) {
        int g = t + i * 256;
        int col = g >> 4, sec = g & 15;
        *(bf16x8*)(Ws + sec * NCOL * 8 + ((col ^ (sec & 7)) * 8)) =
            *(const bf16x8*)(Wtl + g * 8);
    }
    __syncthreads();
    // phase 2: a_h*b_l
#pragma unroll
    for (int k = 0; k < 4; k++) {
        int sec = k * 4 + q;
#pragma unroll
        for (int ct = 0; ct < CT; ct++) {
            bf16x8 bl = *(const bf16x8*)(Ws + sec * NCOL * 8 +
                                         (((ct * 16 + m) ^ (sec & 7)) * 8));
            acc[0][ct] = __builtin_amdgcn_mfma_f32_16x16x32_bf16(ah[0][k], bl, acc[0][ct], 0, 0, 0);
            acc[1][ct] = __builtin_amdgcn_mfma_f32_16x16x32_bf16(ah[1][k], bl, acc[1][ct], 0, 0, 0);
        }
    }

#pragma unroll
    for (int rt = 0; rt < 2; rt++) {
        int rb = r0 + rt * 16 + q * 4;
#pragma unroll
        for (int reg = 0; reg < 4; reg++) {
            int row = rb + reg;
            if (row < n) {
                float s = scale[row];
#pragma unroll
                for (int ct = 0; ct < CT; ct++) {
                    float v = acc[rt][ct][reg] * s;
                    size_t o = (size_t)row * NCOL + ct * 16 + m;
                    if (HALF_OUT) ((__half*)outv)[o] = __float2half(v);
                    else ((float*)outv)[o] = v;
                }
            }
        }
    }
}

// ------- XCD-sliced fp16 aggregation: slice = blockIdx & (SLICES-1) ---------
// T slice (16 feats, 3.2 MB @128 / 1.6 MB @64) fits a 4 MB per-XCD L2.
// 4-lane teams, 4 fp16/lane (8 B gathers), fp32 accumulate.
// BF16_OUT: write bf16 hi/lo (outA/outB); else fp32 (outA).
template <int NCOL, int SLICES, bool RELU, bool BF16_OUT>
__global__ __launch_bounds__(256) void aggregate_sliced(
    const __half* __restrict__ Tm, const int* __restrict__ row_off,
    const int* __restrict__ csr, const float* __restrict__ ndst,
    const float* __restrict__ bias, void* __restrict__ outA,
    unsigned short* __restrict__ outB, int n)
{
    constexpr int SH = (SLICES == 8) ? 3 : 2;
    int slice = blockIdx.x & (SLICES - 1);
    int g = blockIdx.x >> SH;
    int team = threadIdx.x >> 2;      // 64 teams per block
    int li = threadIdx.x & 3;
    int fb = slice * 16 + li * 4;
    int v = g * 64 + team;
    if (v >= n) return;
    float4 bb = *(const float4*)(bias + fb);
    int s = row_off[v], e = row_off[v + 1];
    float nd = ndst[v];
    float a0 = 0.f, a1 = 0.f, a2 = 0.f, a3 = 0.f;
    int i = s;
    for (; i + 4 <= e; i += 4) {
        int u0 = csr[i], u1 = csr[i + 1], u2 = csr[i + 2], u3 = csr[i + 3];
        union { uint2 q; __half h[4]; } U0, U1, U2, U3;
        U0.q = *(const uint2*)(Tm + (size_t)u0 * NCOL + fb);
        U1.q = *(const uint2*)(Tm + (size_t)u1 * NCOL + fb);
        U2.q = *(const uint2*)(Tm + (size_t)u2 * NCOL + fb);
        U3.q = *(const uint2*)(Tm + (size_t)u3 * NCOL + fb);
        a0 += (__half2float(U0.h[0]) + __half2float(U1.h[0])) +
              (__half2float(U2.h[0]) + __half2float(U3.h[0]));
        a1 += (__half2float(U0.h[1]) + __half2float(U1.h[1])) +
              (__half2float(U2.h[1]) + __half2float(U3.h[1]));
        a2 += (__half2float(U0.h[2]) + __half2float(U1.h[2])) +
              (__half2float(U2.h[2]) + __half2float(U3.h[2]));
        a3 += (__half2float(U0.h[3]) + __half2float(U1.h[3])) +
              (__half2float(U2.h[3]) + __half2float(U3.h[3]));
    }
    for (; i < e; i++) {
        int u = csr[i];
        union { uint2 q; __half h[4]; } U;
        U.q = *(const uint2*)(Tm + (size_t)u * NCOL + fb);
        a0 += __half2float(U.h[0]);
        a1 += __half2float(U.h[1]);
        a2 += __half2float(U.h[2]);
        a3 += __half2float(U.h[3]);
    }
    float o0 = nd * a0 + bb.x, o1 = nd * a1 + bb.y;
    float o2 = nd * a2 + bb.z, o3 = nd * a3 + bb.w;
    if (RELU) {
        o0 = fmaxf(o0, 0.f); o1 = fmaxf(o1, 0.f);
        o2 = fmaxf(o2, 0.f); o3 = fmaxf(o3, 0.f);
    }
    if (BF16_OUT) {
        union { uint2 q; unsigned short u[4]; } H, L;
        float o[4] = {o0, o1, o2, o3};
#pragma unroll
        for (int j = 0; j < 4; j++) {
            H.u[j] = bf16_rne(o[j]);
            L.u[j] = bf16_rne(o[j] - bf16_f(H.u[j]));
        }
        *(uint2*)((unsigned short*)outA + (size_t)v * NCOL + fb) = H.q;
        *(uint2*)(outB + (size_t)v * NCOL + fb) = L.q;
    } else {
        *(float4*)((float*)outA + (size_t)v * NCOL + fb) = make_float4(o0, o1, o2, o3);
    }
}

// ---------------- launch ----------------
extern "C" void kernel_launch(void* const* d_in, const int* in_sizes, int n_in,
                              void* d_out, int out_size, void* d_ws, size_t ws_size,
                              hipStream_t stream)
{
    const float* features = (const float*)d_in[0];
    const int* src = (const int*)d_in[1];
    const int* dst = (const int*)d_in[2];
    const float* W0 = (const float*)d_in[3];
    const float* b0 = (const float*)d_in[4];
    const float* W1 = (const float*)d_in[5];
    const float* b1 = (const float*)d_in[6];
    const float* W2 = (const float*)d_in[7];
    const float* b2 = (const float*)d_in[8];

    int n = in_sizes[0] / K_FEATS;  // 100000
    int ne = in_sizes[1];           // 1600000
    int n_pad = (n + 127) & ~127;   // 100096

    char* ws = (char*)d_ws;
    size_t off = 0;
    auto take = [&](size_t bytes) -> char* {
        char* p = ws + off;
        off = (off + bytes + 255) & ~(size_t)255;
        return p;
    };
    unsigned short* XBh = (unsigned short*)take((size_t)n_pad * 128 * 2);
    unsigned short* XBl = (unsigned short*)take((size_t)n_pad * 128 * 2);
    char* Tbuf = take((size_t)n_pad * 128 * 2);   // fp16 [n][128] or [n][64]
    int* csr = (int*)take((size_t)ne * 4);
    int* edge_bkt = (int*)take((size_t)ne * 4);
    unsigned short* src_bkt = (unsigned short*)take((size_t)ne * 2);
    int* row_off = (int*)take((size_t)(n + 1) * 4);
    float* norm_src = (float*)take((size_t)n * 4);
    float* norm_dst = (float*)take((size_t)n * 4);
    unsigned short* W0th = (unsigned short*)take(128 * 128 * 2);
    unsigned short* W0tl = (unsigned short*)take(128 * 128 * 2);
    unsigned short* W1th = (unsigned short*)take(128 * 128 * 2);
    unsigned short* W1tl = (unsigned short*)take(128 * 128 * 2);
    unsigned short* W2th = (unsigned short*)take(64 * 128 * 2);
    unsigned short* W2tl = (unsigned short*)take(64 * 128 * 2);

    int NB = (n + RB - 1) >> RBSHIFT;        // 196 (must be <= 256)
    int chunkA = 8192;
    int C = (ne + chunkA - 1) / chunkA;
    if (C > 256) { chunkA = (ne + 255) / 256; C = (ne + chunkA - 1) / chunkA; }

    int* partialS = (int*)take((size_t)NB * C * 4);
    int* partialD = (int*)take((size_t)NB * C * 4);
    int* totS = (int*)take((size_t)NB * 4);
    int* totD = (int*)take((size_t)NB * 4);
    int* offS = (int*)take((size_t)(NB + 1) * 4);
    int* offD = (int*)take((size_t)(NB + 1) * 4);

    split_w3<<<160, 256, 0, stream>>>(W0, W1, W2, W0th, W0tl, W1th, W1tl, W2th, W2tl);

    // CSR build (two-level counting sort, packed records, fused fine pass)
    bucket_count<<<dim3(C, 2), 256, 0, stream>>>(src, dst, partialS, partialD,
                                                 ne, chunkA, C, NB);
    bucket_prefix<<<dim3(NB, 2), 256, 0, stream>>>(partialS, partialD, totS, totD, C, NB);
    bucket_off_kernel<<<1, 256, 0, stream>>>(totS, totD, offS, offD, row_off, NB, n, ne);
    bucket_scatter<<<C, 256, 0, stream>>>(src, dst, partialS, partialD,
                                          offS, offD, src_bkt, edge_bkt,
                                          ne, chunkA, C, NB);
    fine_all<<<dim3(NB, 2), 256, 0, stream>>>(edge_bkt, src_bkt, offD, offS,
                                              row_off, norm_dst, norm_src, csr, n);

    int gblocks = n_pad / 128;
    int ngroups = (n + 63) / 64;
    __half* Th = (__half*)Tbuf;

    // layer 0 (fp32 features read directly; in-register split)
    gemm_mfma<128, true, true><<<gblocks, 256, 0, stream>>>(
        nullptr, nullptr, features, W0th, W0tl, norm_src, Th, n);
    aggregate_sliced<128, 8, true, true><<<ngroups * 8, 256, 0, stream>>>(
        Th, row_off, csr, norm_dst, b0, XBh, XBl, n);
    // layer 1
    gemm_mfma<128, true, false><<<gblocks, 256, 0, stream>>>(
        XBh, XBl, nullptr, W1th, W1tl, norm_src, Th, n);
    aggregate_sliced<128, 8, true, true><<<ngroups * 8, 256, 0, stream>>>(
        Th, row_off, csr, norm_dst, b1, XBh, XBl, n);
    // layer 2 (NCOL=64, fp16 T, fp32 out, no relu)
    gemm_mfma<64, true, false><<<gblocks, 256, 0, stream>>>(
        XBh, XBl, nullptr, W2th, W2tl, norm_src, Th, n);
    aggregate_sliced<64, 4, false, false><<<ngroups * 4, 256, 0, stream>>>(
        Th, row_off, csr, norm_dst, b2, d_out, nullptr, n);
}

// Round 10
// 375.599 us; speedup vs baseline: 1.9941x; 1.9941x over previous
//
#include <hip/hip_runtime.h>
#include <hip/hip_fp16.h>

#define K_FEATS 128
#define RBSHIFT 9
#define RB 512        // fine-bucket node range (pow2); NB = ceil(n/512) <= 256

typedef short bf16x8 __attribute__((ext_vector_type(8)));
typedef float f32x4 __attribute__((ext_vector_type(4)));

__device__ __forceinline__ unsigned short bf16_rne(float x) {
    unsigned u = __float_as_uint(x);
    unsigned r = (u + 0x7FFFu + ((u >> 16) & 1u)) >> 16;
    return (unsigned short)r;
}
__device__ __forceinline__ float bf16_f(unsigned short h) {
    return __uint_as_float(((unsigned)h) << 16);
}

// ---------------- prep: transpose+split all three W in one dispatch ---------
__global__ __launch_bounds__(256) void split_w3(
    const float* __restrict__ W0, const float* __restrict__ W1,
    const float* __restrict__ W2,
    unsigned short* __restrict__ W0th, unsigned short* __restrict__ W0tl,
    unsigned short* __restrict__ W1th, unsigned short* __restrict__ W1tl,
    unsigned short* __restrict__ W2th, unsigned short* __restrict__ W2tl)
{
    int e = blockIdx.x * 256 + threadIdx.x;
    const float* W;
    unsigned short *Wh, *Wl;
    int NC, idx;
    if (e < 16384)      { W = W0; Wh = W0th; Wl = W0tl; NC = 128; idx = e; }
    else if (e < 32768) { W = W1; Wh = W1th; Wl = W1tl; NC = 128; idx = e - 16384; }
    else if (e < 40960) { W = W2; Wh = W2th; Wl = W2tl; NC = 64;  idx = e - 32768; }
    else return;
    int c = idx >> 7, k = idx & 127;
    float w = W[k * NC + c];
    unsigned short h = bf16_rne(w);
    Wh[idx] = h;
    Wl[idx] = bf16_rne(w - bf16_f(h));
}

// ------- coarse count: both keys in one pass (reads src+dst once) -----------
__global__ __launch_bounds__(256) void bucket_count(
    const int* __restrict__ src, const int* __restrict__ dst,
    int* __restrict__ partialS, int* __restrict__ partialD,
    int ne, int chunkA, int C, int NB)
{
    __shared__ int hS[256];
    __shared__ int hD[256];
    int c = blockIdx.x, t = threadIdx.x;
    if (t < NB) { hS[t] = 0; hD[t] = 0; }
    __syncthreads();
    int e0 = c * chunkA, e1 = min(ne, e0 + chunkA);
    for (int e = e0 + t; e < e1; e += 256) {
        atomicAdd(&hS[src[e] >> RBSHIFT], 1);
        atomicAdd(&hD[dst[e] >> RBSHIFT], 1);
    }
    __syncthreads();
    for (int i = t; i < NB; i += 256) {
        partialS[i * C + c] = hS[i];
        partialD[i * C + c] = hD[i];
    }
}

__global__ __launch_bounds__(256) void bucket_prefix(
    int* __restrict__ partialS, int* __restrict__ partialD,
    int* __restrict__ totS, int* __restrict__ totD, int C, int NB)
{
    __shared__ int sh[256];
    int b = blockIdx.x, t = threadIdx.x;
    int* part = blockIdx.y ? partialD : partialS;
    int* tot = blockIdx.y ? totD : totS;
    int v = (t < C) ? part[b * C + t] : 0;
    sh[t] = v;
    __syncthreads();
    for (int off = 1; off < 256; off <<= 1) {
        int x = (t >= off) ? sh[t - off] : 0;
        __syncthreads();
        sh[t] += x;
        __syncthreads();
    }
    if (t < C) part[b * C + t] = sh[t] - v;
    if (t == 255) tot[b] = sh[255];
}

__global__ __launch_bounds__(256) void bucket_off_kernel(
    const int* __restrict__ totS, const int* __restrict__ totD,
    int* __restrict__ offS, int* __restrict__ offD,
    int* __restrict__ row_off, int NB, int n, int ne)
{
    __shared__ int sh[256];
    int t = threadIdx.x;
    if (t == 0) row_off[n] = ne;
    for (int a = 0; a < 2; a++) {
        const int* tot = a ? totD : totS;
        int* boff = a ? offD : offS;
        int v = (t < NB) ? tot[t] : 0;
        sh[t] = v;
        __syncthreads();
        for (int off = 1; off < 256; off <<= 1) {
            int x = (t >= off) ? sh[t - off] : 0;
            __syncthreads();
            sh[t] += x;
            __syncthreads();
        }
        if (t < NB) boff[t] = sh[t] - v;
        if (t == NB - 1) boff[NB] = sh[t];
        __syncthreads();
    }
}

// ------- coarse scatter (single pass, both arrays, packed records) ----------
__global__ __launch_bounds__(256) void bucket_scatter(
    const int* __restrict__ src, const int* __restrict__ dst,
    const int* __restrict__ partialS, const int* __restrict__ partialD,
    const int* __restrict__ offS, const int* __restrict__ offD,
    unsigned short* __restrict__ src_bkt, int* __restrict__ edge_bkt,
    int ne, int chunkA, int C, int NB)
{
    __shared__ int curS[256];
    __shared__ int curD[256];
    int c = blockIdx.x, t = threadIdx.x;
    if (t < NB) {
        curS[t] = offS[t] + partialS[t * C + c];
        curD[t] = offD[t] + partialD[t * C + c];
    }
    __syncthreads();
    int e0 = c * chunkA, e1 = min(ne, e0 + chunkA);
    for (int e = e0 + t; e < e1; e += 256) {
        int s = src[e];
        int d = dst[e];
        int posD = atomicAdd(&curD[d >> RBSHIFT], 1);
        edge_bkt[posD] = ((d & (RB - 1)) << 17) | s;
        int posS = atomicAdd(&curS[s >> RBSHIFT], 1);
        src_bkt[posS] = (unsigned short)(s & (RB - 1));
    }
}

// ------- fused fine pass: y=0 dst (hist+scan->row_off/norm_dst + scatter),
//         y=1 src (hist->norm_src) -------------------------------------------
__global__ __launch_bounds__(256) void fine_all(
    const int* __restrict__ edge_bkt, const unsigned short* __restrict__ src_bkt,
    const int* __restrict__ offD, const int* __restrict__ offS,
    int* __restrict__ row_off, float* __restrict__ norm_dst,
    float* __restrict__ norm_src, int* __restrict__ csr, int n)
{
    __shared__ int h[RB];
    __shared__ int ps[256];
    int b = blockIdx.x, t = threadIdx.x;
    int lo = b << RBSHIFT;
    for (int i = t; i < RB; i += 256) h[i] = 0;
    __syncthreads();
    if (blockIdx.y == 1) {
        int e1 = offS[b + 1];
        for (int e = offS[b] + t; e < e1; e += 256)
            atomicAdd(&h[src_bkt[e]], 1);
        __syncthreads();
        for (int i = t; i < RB; i += 256) {
            int g = lo + i;
            if (g < n) norm_src[g] = rsqrtf((float)max(h[i], 1));
        }
        return;
    }
    int ebase = offD[b];
    int e1 = offD[b + 1];
    for (int e = ebase + t; e < e1; e += 256)
        atomicAdd(&h[(unsigned)edge_bkt[e] >> 17], 1);
    __syncthreads();
    int v0 = h[2 * t], v1 = h[2 * t + 1];
    ps[t] = v0 + v1;
    __syncthreads();
    for (int off = 1; off < 256; off <<= 1) {
        int x = (t >= off) ? ps[t - off] : 0;
        __syncthreads();
        ps[t] += x;
        __syncthreads();
    }
    int excl = ps[t] - (v0 + v1) + ebase;
    int g0 = lo + 2 * t, g1 = g0 + 1;
    if (g0 < n) { row_off[g0] = excl;      norm_dst[g0] = rsqrtf((float)max(v0, 1)); }
    if (g1 < n) { row_off[g1] = excl + v0; norm_dst[g1] = rsqrtf((float)max(v1, 1)); }
    h[2 * t] = excl;          // cursors
    h[2 * t + 1] = excl + v0;
    __syncthreads();
    for (int e = ebase + t; e < e1; e += 256) {
        int p = edge_bkt[e];
        int pos = atomicAdd(&h[(unsigned)p >> 17], 1);
        csr[pos] = p & 0x1FFFF;
    }
}

// ---------------- MFMA GEMM: out = scale ⊙ (X @ W), bf16 hi/lo split --------
// MODE 0: Xf fp32 [n][128] (guarded reads, in-register split)
// MODE 1: X16 fp16 [n_pad][128] (in-register split; fp16->bf16 hi/lo is EXACT)
// W staged in LDS (XOR-swizzled), 3 barriers total.
template <int NCOL, bool HALF_OUT, int MODE>
__global__ __launch_bounds__(256) void gemm_mfma(
    const __half* __restrict__ X16, const float* __restrict__ Xf,
    const unsigned short* __restrict__ Wth, const unsigned short* __restrict__ Wtl,
    const float* __restrict__ scale, void* __restrict__ outv, int n)
{
    constexpr int CT = NCOL / 16;
    constexpr int CHUNKS = NCOL * 16;          // 16B chunks per half
    __shared__ unsigned short Ws[16 * NCOL * 8];  // [sec][col^(sec&7)][8]

    int t = threadIdx.x;
    int w = t >> 6, lane = t & 63, m = lane & 15, q = lane >> 4;
    int r0 = blockIdx.x * 128 + w * 32;

    f32x4 acc[2][CT];
#pragma unroll
    for (int i = 0; i < 2; i++)
#pragma unroll
        for (int j = 0; j < CT; j++) acc[i][j] = (f32x4){0.f, 0.f, 0.f, 0.f};

    // all A fragments up front, split in-register
    bf16x8 ah[2][4], al[2][4];
#pragma unroll
    for (int rt = 0; rt < 2; rt++) {
        int row = r0 + rt * 16 + m;
        size_t base = (size_t)row * K_FEATS + q * 8;
#pragma unroll
        for (int k = 0; k < 4; k++) {
            float f[8];
            if (MODE == 0) {
                if (row < n) {
                    *(float4*)&f[0] = *(const float4*)(Xf + base + k * 32);
                    *(float4*)&f[4] = *(const float4*)(Xf + base + k * 32 + 4);
                } else {
#pragma unroll
                    for (int j = 0; j < 8; j++) f[j] = 0.f;
                }
            } else {
                union { uint4 q4; __half h[8]; } U;
                U.q4 = *(const uint4*)(X16 + base + k * 32);
#pragma unroll
                for (int j = 0; j < 8; j++) f[j] = __half2float(U.h[j]);
            }
            union { bf16x8 v; unsigned short u[8]; } H, L;
#pragma unroll
            for (int j = 0; j < 8; j++) {
                H.u[j] = bf16_rne(f[j]);
                L.u[j] = bf16_rne(f[j] - bf16_f(H.u[j]));
            }
            ah[rt][k] = H.v;
            al[rt][k] = L.v;
        }
    }

    // stage W-hi
#pragma unroll
    for (int i = 0; i < CHUNKS / 256; i++) {
        int g = t + i * 256;
        int col = g >> 4, sec = g & 15;
        *(bf16x8*)(Ws + sec * NCOL * 8 + ((col ^ (sec & 7)) * 8)) =
            *(const bf16x8*)(Wth + g * 8);
    }
    __syncthreads();
    // phase 1: a_h*b_h + a_l*b_h
#pragma unroll
    for (int k = 0; k < 4; k++) {
        int sec = k * 4 + q;
#pragma unroll
        for (int ct = 0; ct < CT; ct++) {
            bf16x8 bh = *(const bf16x8*)(Ws + sec * NCOL * 8 +
                                         (((ct * 16 + m) ^ (sec & 7)) * 8));
            acc[0][ct] = __builtin_amdgcn_mfma_f32_16x16x32_bf16(ah[0][k], bh, acc[0][ct], 0, 0, 0);
            acc[0][ct] = __builtin_amdgcn_mfma_f32_16x16x32_bf16(al[0][k], bh, acc[0][ct], 0, 0, 0);
            acc[1][ct] = __builtin_amdgcn_mfma_f32_16x16x32_bf16(ah[1][k], bh, acc[1][ct], 0, 0, 0);
            acc[1][ct] = __builtin_amdgcn_mfma_f32_16x16x32_bf16(al[1][k], bh, acc[1][ct], 0, 0, 0);
        }
    }
    __syncthreads();
    // stage W-lo
#pragma unroll
    for (int i = 0; i < CHUNKS / 256; i++) {
        int g = t + i * 256;
        int col = g >> 4, sec = g & 15;
        *(bf16x8*)(Ws + sec * NCOL * 8 + ((col ^ (sec & 7)) * 8)) =
            *(const bf16x8*)(Wtl + g * 8);
    }
    __syncthreads();
    // phase 2: a_h*b_l
#pragma unroll
    for (int k = 0; k < 4; k++) {
        int sec = k * 4 + q;
#pragma unroll
        for (int ct = 0; ct < CT; ct++) {
            bf16x8 bl = *(const bf16x8*)(Ws + sec * NCOL * 8 +
                                         (((ct * 16 + m) ^ (sec & 7)) * 8));
            acc[0][ct] = __builtin_amdgcn_mfma_f32_16x16x32_bf16(ah[0][k], bl, acc[0][ct], 0, 0, 0);
            acc[1][ct] = __builtin_amdgcn_mfma_f32_16x16x32_bf16(ah[1][k], bl, acc[1][ct], 0, 0, 0);
        }
    }

#pragma unroll
    for (int rt = 0; rt < 2; rt++) {
        int rb = r0 + rt * 16 + q * 4;
#pragma unroll
        for (int reg = 0; reg < 4; reg++) {
            int row = rb + reg;
            if (row < n) {
                float s = scale[row];
#pragma unroll
                for (int ct = 0; ct < CT; ct++) {
                    float v = acc[rt][ct][reg] * s;
                    size_t o = (size_t)row * NCOL + ct * 16 + m;
                    if (HALF_OUT) ((__half*)outv)[o] = __float2half(v);
                    else ((float*)outv)[o] = v;
                }
            }
        }
    }
}

// ---------------- fp16-gather aggregation (128 feats) -> fp16 out -----------
// 16-lane teams, 8 fp16 feats/lane, 4 edges in flight (round-6/8 form)
template <bool RELU>
__global__ __launch_bounds__(256) void aggregate4h(
    const __half* __restrict__ Tm, const int* __restrict__ row_off,
    const int* __restrict__ csr, const float* __restrict__ ndst,
    const float* __restrict__ bias, __half* __restrict__ Oh, int n)
{
    int lane = threadIdx.x & 15;
    int team = threadIdx.x >> 4;
    int fb = lane * 8;
    float b[8];
    *(float4*)&b[0] = *(const float4*)(bias + fb);
    *(float4*)&b[4] = *(const float4*)(bias + fb + 4);
    int stride = gridDim.x * 16;
    for (int v = blockIdx.x * 16 + team; v < n; v += stride) {
        int s = row_off[v], e = row_off[v + 1];
        float nd = ndst[v];
        float a[8] = {};
        int i = s;
        for (; i + 4 <= e; i += 4) {
            int u0 = csr[i], u1 = csr[i + 1], u2 = csr[i + 2], u3 = csr[i + 3];
            union { uint4 q; __half h[8]; } U0, U1, U2, U3;
            U0.q = *(const uint4*)(Tm + (size_t)u0 * 128 + fb);
            U1.q = *(const uint4*)(Tm + (size_t)u1 * 128 + fb);
            U2.q = *(const uint4*)(Tm + (size_t)u2 * 128 + fb);
            U3.q = *(const uint4*)(Tm + (size_t)u3 * 128 + fb);
#pragma unroll
            for (int j = 0; j < 8; j++)
                a[j] += (__half2float(U0.h[j]) + __half2float(U1.h[j])) +
                        (__half2float(U2.h[j]) + __half2float(U3.h[j]));
        }
        for (; i < e; i++) {
            int u = csr[i];
            union { uint4 q; __half h[8]; } U;
            U.q = *(const uint4*)(Tm + (size_t)u * 128 + fb);
#pragma unroll
            for (int j = 0; j < 8; j++) a[j] += __half2float(U.h[j]);
        }
        union { uint4 q; __half h[8]; } O;
#pragma unroll
        for (int j = 0; j < 8; j++) {
            float o = nd * a[j] + b[j];
            if (RELU) o = fmaxf(o, 0.f);
            O.h[j] = __float2half(o);
        }
        *(uint4*)(Oh + (size_t)v * 128 + fb) = O.q;
    }
}

// ------- final aggregation: fp16 T (64 feats), fp32 out, 8-lane teams -------
__global__ __launch_bounds__(256) void aggregate2h(
    const __half* __restrict__ Tm, const int* __restrict__ row_off,
    const int* __restrict__ csr, const float* __restrict__ ndst,
    const float* __restrict__ bias, float* __restrict__ out, int n)
{
    int lane = threadIdx.x & 7;
    int team = threadIdx.x >> 3;      // 32 teams/block
    int fb = lane * 8;
    float b[8];
    *(float4*)&b[0] = *(const float4*)(bias + fb);
    *(float4*)&b[4] = *(const float4*)(bias + fb + 4);
    int stride = gridDim.x * 32;
    for (int v = blockIdx.x * 32 + team; v < n; v += stride) {
        int s = row_off[v], e = row_off[v + 1];
        float nd = ndst[v];
        float a[8] = {};
        int i = s;
        for (; i + 4 <= e; i += 4) {
            int u0 = csr[i], u1 = csr[i + 1], u2 = csr[i + 2], u3 = csr[i + 3];
            union { uint4 q; __half h[8]; } U0, U1, U2, U3;
            U0.q = *(const uint4*)(Tm + (size_t)u0 * 64 + fb);
            U1.q = *(const uint4*)(Tm + (size_t)u1 * 64 + fb);
            U2.q = *(const uint4*)(Tm + (size_t)u2 * 64 + fb);
            U3.q = *(const uint4*)(Tm + (size_t)u3 * 64 + fb);
#pragma unroll
            for (int j = 0; j < 8; j++)
                a[j] += (__half2float(U0.h[j]) + __half2float(U1.h[j])) +
                        (__half2float(U2.h[j]) + __half2float(U3.h[j]));
        }
        for (; i < e; i++) {
            int u = csr[i];
            union { uint4 q; __half h[8]; } U;
            U.q = *(const uint4*)(Tm + (size_t)u * 64 + fb);
#pragma unroll
            for (int j = 0; j < 8; j++) a[j] += __half2float(U.h[j]);
        }
        float o[8];
#pragma unroll
        for (int j = 0; j < 8; j++) o[j] = nd * a[j] + b[j];
        *(float4*)(out + (size_t)v * 64 + fb) = *(float4*)&o[0];
        *(float4*)(out + (size_t)v * 64 + fb + 4) = *(float4*)&o[4];
    }
}

// ---------------- launch ----------------
extern "C" void kernel_launch(void* const* d_in, const int* in_sizes, int n_in,
                              void* d_out, int out_size, void* d_ws, size_t ws_size,
                              hipStream_t stream)
{
    const float* features = (const float*)d_in[0];
    const int* src = (const int*)d_in[1];
    const int* dst = (const int*)d_in[2];
    const float* W0 = (const float*)d_in[3];
    const float* b0 = (const float*)d_in[4];
    const float* W1 = (const float*)d_in[5];
    const float* b1 = (const float*)d_in[6];
    const float* W2 = (const float*)d_in[7];
    const float* b2 = (const float*)d_in[8];

    int n = in_sizes[0] / K_FEATS;  // 100000
    int ne = in_sizes[1];           // 1600000
    int n_pad = (n + 127) & ~127;   // 100096

    char* ws = (char*)d_ws;
    size_t off = 0;
    auto take = [&](size_t bytes) -> char* {
        char* p = ws + off;
        off = (off + bytes + 255) & ~(size_t)255;
        return p;
    };
    __half* Xbuf = (__half*)take((size_t)n_pad * 128 * 2);  // h (fp16) ping
    __half* Th = (__half*)take((size_t)n_pad * 128 * 2);    // T (fp16) pong
    int* csr = (int*)take((size_t)ne * 4);
    int* edge_bkt = (int*)take((size_t)ne * 4);
    unsigned short* src_bkt = (unsigned short*)take((size_t)ne * 2);
    int* row_off = (int*)take((size_t)(n + 1) * 4);
    float* norm_src = (float*)take((size_t)n * 4);
    float* norm_dst = (float*)take((size_t)n * 4);
    unsigned short* W0th = (unsigned short*)take(128 * 128 * 2);
    unsigned short* W0tl = (unsigned short*)take(128 * 128 * 2);
    unsigned short* W1th = (unsigned short*)take(128 * 128 * 2);
    unsigned short* W1tl = (unsigned short*)take(128 * 128 * 2);
    unsigned short* W2th = (unsigned short*)take(64 * 128 * 2);
    unsigned short* W2tl = (unsigned short*)take(64 * 128 * 2);

    int NB = (n + RB - 1) >> RBSHIFT;        // 196 (must be <= 256)
    int chunkA = 8192;
    int C = (ne + chunkA - 1) / chunkA;
    if (C > 256) { chunkA = (ne + 255) / 256; C = (ne + chunkA - 1) / chunkA; }

    int* partialS = (int*)take((size_t)NB * C * 4);
    int* partialD = (int*)take((size_t)NB * C * 4);
    int* totS = (int*)take((size_t)NB * 4);
    int* totD = (int*)take((size_t)NB * 4);
    int* offS = (int*)take((size_t)(NB + 1) * 4);
    int* offD = (int*)take((size_t)(NB + 1) * 4);

    split_w3<<<160, 256, 0, stream>>>(W0, W1, W2, W0th, W0tl, W1th, W1tl, W2th, W2tl);

    // CSR build (two-level counting sort, packed records, fused fine pass)
    bucket_count<<<C, 256, 0, stream>>>(src, dst, partialS, partialD,
                                        ne, chunkA, C, NB);
    bucket_prefix<<<dim3(NB, 2), 256, 0, stream>>>(partialS, partialD, totS, totD, C, NB);
    bucket_off_kernel<<<1, 256, 0, stream>>>(totS, totD, offS, offD, row_off, NB, n, ne);
    bucket_scatter<<<C, 256, 0, stream>>>(src, dst, partialS, partialD,
                                          offS, offD, src_bkt, edge_bkt,
                                          ne, chunkA, C, NB);
    fine_all<<<dim3(NB, 2), 256, 0, stream>>>(edge_bkt, src_bkt, offD, offS,
                                              row_off, norm_dst, norm_src, csr, n);

    int gblocks = n_pad / 128;
    int ablocks4 = (n + 15) / 16;
    int ablocks2 = (n + 31) / 32;

    // layer 0 (fp32 features read directly; in-register split) -> Th -> Xbuf
    gemm_mfma<128, true, 0><<<gblocks, 256, 0, stream>>>(
        nullptr, features, W0th, W0tl, norm_src, Th, n);
    aggregate4h<true><<<ablocks4, 256, 0, stream>>>(Th, row_off, csr, norm_dst, b0,
                                                    Xbuf, n);
    // layer 1 (fp16 in, exact in-register split)
    gemm_mfma<128, true, 1><<<gblocks, 256, 0, stream>>>(
        Xbuf, nullptr, W1th, W1tl, norm_src, Th, n);
    aggregate4h<true><<<ablocks4, 256, 0, stream>>>(Th, row_off, csr, norm_dst, b1,
                                                    Xbuf, n);
    // layer 2 (NCOL=64, fp16 T, fp32 out, no relu)
    gemm_mfma<64, true, 1><<<gblocks, 256, 0, stream>>>(
        Xbuf, nullptr, W2th, W2tl, norm_src, Th, n);
    aggregate2h<<<ablocks2, 256, 0, stream>>>(Th, row_off, csr, norm_dst, b2,
                                              (float*)d_out, n);
}